// Round 1
// baseline (2283.011 us; speedup 1.0000x reference)
//
#include <hip/hip_runtime.h>

#define NN 50000
#define NE 640000
#define CH 128

// ---- GEMM: Y = X @ W. X:[n,128] W:[128,128] Y:[n,128], fp32 vector ALU ----
// 256 threads/block, 32 rows/block, each thread computes 4 rows x 4 cols.
__global__ __launch_bounds__(256) void gemm128(const float* __restrict__ X,
                                               const float* __restrict__ W,
                                               float* __restrict__ Y, int nrows) {
    __shared__ float Wl[CH * CH];      // 64 KiB
    __shared__ float Xl[32 * CH];      // 16 KiB
    for (int i = threadIdx.x; i < CH * CH; i += 256) Wl[i] = W[i];
    int row0 = blockIdx.x * 32;
    int nr = min(32, nrows - row0);
    for (int i = threadIdx.x; i < nr * CH; i += 256) Xl[i] = X[row0 * CH + i];
    __syncthreads();

    const int cg = threadIdx.x & 31;   // 32 col groups of 4
    const int rg = threadIdx.x >> 5;   // 8 row groups of 4
    const int c0 = cg * 4;
    const int r0 = rg * 4;

    float acc[4][4];
#pragma unroll
    for (int r = 0; r < 4; ++r)
#pragma unroll
        for (int c = 0; c < 4; ++c) acc[r][c] = 0.f;

#pragma unroll 8
    for (int k4 = 0; k4 < CH / 4; ++k4) {
        float4 xv[4];
#pragma unroll
        for (int r = 0; r < 4; ++r)
            xv[r] = *(const float4*)&Xl[(r0 + r) * CH + k4 * 4];
#pragma unroll
        for (int kk = 0; kk < 4; ++kk) {
            float4 wv = *(const float4*)&Wl[(k4 * 4 + kk) * CH + c0];
#pragma unroll
            for (int r = 0; r < 4; ++r) {
                float xs = (kk == 0) ? xv[r].x : (kk == 1) ? xv[r].y
                         : (kk == 2) ? xv[r].z : xv[r].w;
                acc[r][0] += xs * wv.x;
                acc[r][1] += xs * wv.y;
                acc[r][2] += xs * wv.z;
                acc[r][3] += xs * wv.w;
            }
        }
    }

#pragma unroll
    for (int r = 0; r < 4; ++r) {
        int row = row0 + r0 + r;
        if (row < nrows)
            *(float4*)&Y[row * CH + c0] =
                make_float4(acc[r][0], acc[r][1], acc[r][2], acc[r][3]);
    }
}

// ---- scatter: AGG[dst[e]] += H[src[e]]  (row-wise, 32 lanes/edge, float4) ----
__global__ __launch_bounds__(256) void scatter_add(const float* __restrict__ H,
                                                   const int* __restrict__ srcIdx,
                                                   const int* __restrict__ dstIdx,
                                                   float* __restrict__ AGG) {
    int e = blockIdx.x * 8 + (threadIdx.x >> 5);
    if (e >= NE) return;
    int lane = threadIdx.x & 31;
    int s = srcIdx[e];
    int d = dstIdx[e];
    float4 v = *(const float4*)&H[s * CH + lane * 4];
    float* p = &AGG[d * CH + lane * 4];
    atomicAdd(p + 0, v.x);
    atomicAdd(p + 1, v.y);
    atomicAdd(p + 2, v.z);
    atomicAdd(p + 3, v.w);
}

// ---- elementwise: O = (A + b[col])  (+relu) , float4 over NN*CH ----
__global__ __launch_bounds__(256) void bias_act(const float* __restrict__ A,
                                                const float* __restrict__ b,
                                                float* __restrict__ O,
                                                int n4, int do_relu) {
    int i = blockIdx.x * 256 + threadIdx.x;
    if (i >= n4) return;
    float4 v = ((const float4*)A)[i];
    int c0 = (i * 4) & (CH - 1);
    v.x += b[c0 + 0];
    v.y += b[c0 + 1];
    v.z += b[c0 + 2];
    v.w += b[c0 + 3];
    if (do_relu) {
        v.x = fmaxf(v.x, 0.f);
        v.y = fmaxf(v.y, 0.f);
        v.z = fmaxf(v.z, 0.f);
        v.w = fmaxf(v.w, 0.f);
    }
    ((float4*)O)[i] = v;
}

extern "C" void kernel_launch(void* const* d_in, const int* in_sizes, int n_in,
                              void* d_out, int out_size, void* d_ws, size_t ws_size,
                              hipStream_t stream) {
    const float* v0 = (const float*)d_in[0];
    const int* edge = (const int*)d_in[1];   // [2, NE]: row0 = src, row1 = dst
    const float* W1 = (const float*)d_in[2];
    const float* b1 = (const float*)d_in[3];
    const float* W2 = (const float*)d_in[4];
    const float* b2 = (const float*)d_in[5];
    float* out = (float*)d_out;

    float* bufA = (float*)d_ws;              // h1, then x
    float* bufB = bufA + (size_t)NN * CH;    // agg1, then h2

    const int* srcIdx = edge;
    const int* dstIdx = edge + NE;

    const int n4 = NN * CH / 4;

    // zero accumulators (deterministic per call)
    hipMemsetAsync(bufB, 0, (size_t)NN * CH * sizeof(float), stream);
    hipMemsetAsync(d_out, 0, (size_t)NN * CH * sizeof(float), stream);

    // layer 1: h1 = v0 @ W1 ; agg1 = scatter(h1) ; x = relu(agg1 + b1)
    gemm128<<<(NN + 31) / 32, 256, 0, stream>>>(v0, W1, bufA, NN);
    scatter_add<<<NE / 8, 256, 0, stream>>>(bufA, srcIdx, dstIdx, bufB);
    bias_act<<<(n4 + 255) / 256, 256, 0, stream>>>(bufB, b1, bufA, n4, 1);

    // layer 2: h2 = x @ W2 ; agg2 = scatter(h2) ; out = agg2 + b2
    gemm128<<<(NN + 31) / 32, 256, 0, stream>>>(bufA, W2, bufB, NN);
    scatter_add<<<NE / 8, 256, 0, stream>>>(bufB, srcIdx, dstIdx, out);
    bias_act<<<(n4 + 255) / 256, 256, 0, stream>>>(out, b2, out, n4, 0);
}

// Round 2
// 351.641 us; speedup vs baseline: 6.4924x; 6.4924x over previous
//
#include <hip/hip_runtime.h>

#define NN 50000
#define NE 640000
#define CH 128

// ---- GEMM: Y = X @ W. X:[n,128] W:[128,128] Y:[n,128], fp32 vector ALU ----
__global__ __launch_bounds__(256) void gemm128(const float* __restrict__ X,
                                               const float* __restrict__ W,
                                               float* __restrict__ Y, int nrows) {
    __shared__ float Wl[CH * CH];      // 64 KiB
    __shared__ float Xl[32 * CH];      // 16 KiB
    for (int i = threadIdx.x; i < CH * CH; i += 256) Wl[i] = W[i];
    int row0 = blockIdx.x * 32;
    int nr = min(32, nrows - row0);
    for (int i = threadIdx.x; i < nr * CH; i += 256) Xl[i] = X[row0 * CH + i];
    __syncthreads();

    const int cg = threadIdx.x & 31;
    const int rg = threadIdx.x >> 5;
    const int c0 = cg * 4;
    const int r0 = rg * 4;

    float acc[4][4];
#pragma unroll
    for (int r = 0; r < 4; ++r)
#pragma unroll
        for (int c = 0; c < 4; ++c) acc[r][c] = 0.f;

#pragma unroll 8
    for (int k4 = 0; k4 < CH / 4; ++k4) {
        float4 xv[4];
#pragma unroll
        for (int r = 0; r < 4; ++r)
            xv[r] = *(const float4*)&Xl[(r0 + r) * CH + k4 * 4];
#pragma unroll
        for (int kk = 0; kk < 4; ++kk) {
            float4 wv = *(const float4*)&Wl[(k4 * 4 + kk) * CH + c0];
#pragma unroll
            for (int r = 0; r < 4; ++r) {
                float xs = (kk == 0) ? xv[r].x : (kk == 1) ? xv[r].y
                         : (kk == 2) ? xv[r].z : xv[r].w;
                acc[r][0] += xs * wv.x;
                acc[r][1] += xs * wv.y;
                acc[r][2] += xs * wv.z;
                acc[r][3] += xs * wv.w;
            }
        }
    }

#pragma unroll
    for (int r = 0; r < 4; ++r) {
        int row = row0 + r0 + r;
        if (row < nrows)
            *(float4*)&Y[row * CH + c0] =
                make_float4(acc[r][0], acc[r][1], acc[r][2], acc[r][3]);
    }
}

// ---- CSR build: count degrees ----
__global__ __launch_bounds__(256) void count_deg(const int* __restrict__ dstIdx,
                                                 int* __restrict__ cnt) {
    int e = blockIdx.x * 256 + threadIdx.x;
    if (e < NE) atomicAdd(&cnt[dstIdx[e]], 1);
}

// ---- CSR build: exclusive scan of 50000 counts (single workgroup) ----
__global__ __launch_bounds__(1024) void scan_nodes(const int* __restrict__ cnt,
                                                   int* __restrict__ start) {
    __shared__ int buf[1024];
    const int CHUNK = (NN + 1023) / 1024;   // 49
    int t = threadIdx.x;
    int base = t * CHUNK;
    int s = 0;
    for (int i = 0; i < CHUNK; ++i) {
        int idx = base + i;
        if (idx < NN) s += cnt[idx];
    }
    buf[t] = s;
    __syncthreads();
    // inclusive Hillis-Steele scan over the 1024 chunk sums
    for (int off = 1; off < 1024; off <<= 1) {
        int v = (t >= off) ? buf[t - off] : 0;
        __syncthreads();
        buf[t] += v;
        __syncthreads();
    }
    int run = buf[t] - s;   // exclusive prefix of this chunk
    for (int i = 0; i < CHUNK; ++i) {
        int idx = base + i;
        if (idx < NN) { start[idx] = run; run += cnt[idx]; }
    }
    if (t == 1023) start[NN] = run;   // last chunk is past NN, run == total == NE
}

// ---- CSR build: fill per-dst src lists ----
__global__ __launch_bounds__(256) void fill_csr(const int* __restrict__ srcIdx,
                                                const int* __restrict__ dstIdx,
                                                const int* __restrict__ start,
                                                int* __restrict__ cursor,
                                                int* __restrict__ esrc) {
    int e = blockIdx.x * 256 + threadIdx.x;
    if (e < NE) {
        int d = dstIdx[e];
        int p = atomicAdd(&cursor[d], 1);
        esrc[start[d] + p] = srcIdx[e];
    }
}

// ---- aggregate: O[n] = sum_{e in CSR[n]} H[esrc[e]] + bias  (+relu) ----
// one wave per node, 2 channels per lane, 4-deep load ILP
__global__ __launch_bounds__(256) void gather_nodes(const float* __restrict__ H,
                                                    const int* __restrict__ start,
                                                    const int* __restrict__ esrc,
                                                    const float* __restrict__ bias,
                                                    float* __restrict__ O,
                                                    int do_relu) {
    int node = blockIdx.x * 4 + (threadIdx.x >> 6);
    if (node >= NN) return;
    int lane = threadIdx.x & 63;
    int s0 = start[node], s1 = start[node + 1];
    float accx = 0.f, accy = 0.f;
    int i = s0;
    for (; i + 3 < s1; i += 4) {
        int sA = esrc[i], sB = esrc[i + 1], sC = esrc[i + 2], sD = esrc[i + 3];
        float2 a = *(const float2*)&H[sA * CH + lane * 2];
        float2 b = *(const float2*)&H[sB * CH + lane * 2];
        float2 c = *(const float2*)&H[sC * CH + lane * 2];
        float2 d = *(const float2*)&H[sD * CH + lane * 2];
        accx += (a.x + b.x) + (c.x + d.x);
        accy += (a.y + b.y) + (c.y + d.y);
    }
    for (; i < s1; ++i) {
        int sA = esrc[i];
        float2 a = *(const float2*)&H[sA * CH + lane * 2];
        accx += a.x;
        accy += a.y;
    }
    float2 bv = *(const float2*)&bias[lane * 2];
    accx += bv.x;
    accy += bv.y;
    if (do_relu) { accx = fmaxf(accx, 0.f); accy = fmaxf(accy, 0.f); }
    *(float2*)&O[node * CH + lane * 2] = make_float2(accx, accy);
}

extern "C" void kernel_launch(void* const* d_in, const int* in_sizes, int n_in,
                              void* d_out, int out_size, void* d_ws, size_t ws_size,
                              hipStream_t stream) {
    const float* v0 = (const float*)d_in[0];
    const int* edge = (const int*)d_in[1];   // [2, NE]: row0 = src, row1 = dst
    const float* W1 = (const float*)d_in[2];
    const float* b1 = (const float*)d_in[3];
    const float* W2 = (const float*)d_in[4];
    const float* b2 = (const float*)d_in[5];
    float* out = (float*)d_out;

    const int* srcIdx = edge;
    const int* dstIdx = edge + NE;

    // workspace layout
    float* bufA = (float*)d_ws;                  // [NN*CH] h1 / h2
    float* bufB = bufA + (size_t)NN * CH;        // [NN*CH] x (layer-1 output)
    int* cnt    = (int*)(bufB + (size_t)NN * CH);// [NN]
    int* cursor = cnt + NN;                      // [NN]
    int* start  = cursor + NN;                   // [NN+1]
    int* esrc   = start + (NN + 1);              // [NE]

    // --- build CSR (per call; deterministic structure) ---
    hipMemsetAsync(cnt, 0, 2 * (size_t)NN * sizeof(int), stream);  // cnt + cursor
    count_deg<<<(NE + 255) / 256, 256, 0, stream>>>(dstIdx, cnt);
    scan_nodes<<<1, 1024, 0, stream>>>(cnt, start);
    fill_csr<<<(NE + 255) / 256, 256, 0, stream>>>(srcIdx, dstIdx, start, cursor, esrc);

    // --- layer 1: x = relu(A @ (v0 W1) + b1) ---
    gemm128<<<(NN + 31) / 32, 256, 0, stream>>>(v0, W1, bufA, NN);
    gather_nodes<<<(NN + 3) / 4, 256, 0, stream>>>(bufA, start, esrc, b1, bufB, 1);

    // --- layer 2: out = A @ (x W2) + b2 ---
    gemm128<<<(NN + 31) / 32, 256, 0, stream>>>(bufB, W2, bufA, NN);
    gather_nodes<<<(NN + 3) / 4, 256, 0, stream>>>(bufA, start, esrc, b2, out, 0);
}

// Round 3
// 268.748 us; speedup vs baseline: 8.4950x; 1.3084x over previous
//
#include <hip/hip_runtime.h>

#define NN 50000
#define NE 640000
#define CH 128
#define SCAN_B 256
#define NBLK ((NN + SCAN_B - 1) / SCAN_B)   // 196

// ---- GEMM: Y = X @ W. X:[n,128] W:[128,128] Y:[n,128], fp32 vector ALU ----
__global__ __launch_bounds__(256) void gemm128(const float* __restrict__ X,
                                               const float* __restrict__ W,
                                               float* __restrict__ Y, int nrows) {
    __shared__ float Wl[CH * CH];      // 64 KiB
    __shared__ float Xl[32 * CH];      // 16 KiB
    for (int i = threadIdx.x; i < CH * CH; i += 256) Wl[i] = W[i];
    int row0 = blockIdx.x * 32;
    int nr = min(32, nrows - row0);
    for (int i = threadIdx.x; i < nr * CH; i += 256) Xl[i] = X[row0 * CH + i];
    __syncthreads();

    const int cg = threadIdx.x & 31;
    const int rg = threadIdx.x >> 5;
    const int c0 = cg * 4;
    const int r0 = rg * 4;

    float acc[4][4];
#pragma unroll
    for (int r = 0; r < 4; ++r)
#pragma unroll
        for (int c = 0; c < 4; ++c) acc[r][c] = 0.f;

#pragma unroll 8
    for (int k4 = 0; k4 < CH / 4; ++k4) {
        float4 xv[4];
#pragma unroll
        for (int r = 0; r < 4; ++r)
            xv[r] = *(const float4*)&Xl[(r0 + r) * CH + k4 * 4];
#pragma unroll
        for (int kk = 0; kk < 4; ++kk) {
            float4 wv = *(const float4*)&Wl[(k4 * 4 + kk) * CH + c0];
#pragma unroll
            for (int r = 0; r < 4; ++r) {
                float xs = (kk == 0) ? xv[r].x : (kk == 1) ? xv[r].y
                         : (kk == 2) ? xv[r].z : xv[r].w;
                acc[r][0] += xs * wv.x;
                acc[r][1] += xs * wv.y;
                acc[r][2] += xs * wv.z;
                acc[r][3] += xs * wv.w;
            }
        }
    }

#pragma unroll
    for (int r = 0; r < 4; ++r) {
        int row = row0 + r0 + r;
        if (row < nrows)
            *(float4*)&Y[row * CH + c0] =
                make_float4(acc[r][0], acc[r][1], acc[r][2], acc[r][3]);
    }
}

// ---- CSR build: count degrees ----
__global__ __launch_bounds__(256) void count_deg(const int* __restrict__ dstIdx,
                                                 int* __restrict__ cnt) {
    int e = blockIdx.x * 256 + threadIdx.x;
    if (e < NE) atomicAdd(&cnt[dstIdx[e]], 1);
}

// ---- scan level 1: per-block sums of 256 counts ----
__global__ __launch_bounds__(256) void scan_bsum(const int* __restrict__ cnt,
                                                 int* __restrict__ bsum) {
    __shared__ int sd[256];
    int i = blockIdx.x * 256 + threadIdx.x;
    sd[threadIdx.x] = (i < NN) ? cnt[i] : 0;
    __syncthreads();
    for (int off = 128; off > 0; off >>= 1) {
        if (threadIdx.x < off) sd[threadIdx.x] += sd[threadIdx.x + off];
        __syncthreads();
    }
    if (threadIdx.x == 0) bsum[blockIdx.x] = sd[0];
}

// ---- scan level 2: exclusive scan of the NBLK block sums (1 block) ----
__global__ __launch_bounds__(256) void scan_bofs(const int* __restrict__ bsum,
                                                 int* __restrict__ bofs,
                                                 int* __restrict__ start) {
    __shared__ int buf[256];
    int t = threadIdx.x;
    int v = (t < NBLK) ? bsum[t] : 0;
    buf[t] = v;
    __syncthreads();
    for (int off = 1; off < 256; off <<= 1) {
        int u = (t >= off) ? buf[t - off] : 0;
        __syncthreads();
        buf[t] += u;
        __syncthreads();
    }
    if (t < NBLK) bofs[t] = buf[t] - v;          // exclusive
    if (t == 0) start[NN] = buf[NBLK - 1];       // total == NE
}

// ---- scan level 3: local exclusive scan + block offset -> start[] ----
__global__ __launch_bounds__(256) void scan_local(const int* __restrict__ cnt,
                                                  const int* __restrict__ bofs,
                                                  int* __restrict__ start) {
    __shared__ int buf[256];
    int t = threadIdx.x;
    int i = blockIdx.x * 256 + t;
    int v = (i < NN) ? cnt[i] : 0;
    buf[t] = v;
    __syncthreads();
    for (int off = 1; off < 256; off <<= 1) {
        int u = (t >= off) ? buf[t - off] : 0;
        __syncthreads();
        buf[t] += u;
        __syncthreads();
    }
    if (i < NN) start[i] = bofs[blockIdx.x] + buf[t] - v;
}

// ---- CSR build: fill per-dst src lists ----
__global__ __launch_bounds__(256) void fill_csr(const int* __restrict__ srcIdx,
                                                const int* __restrict__ dstIdx,
                                                const int* __restrict__ start,
                                                int* __restrict__ cursor,
                                                int* __restrict__ esrc) {
    int e = blockIdx.x * 256 + threadIdx.x;
    if (e < NE) {
        int d = dstIdx[e];
        int p = atomicAdd(&cursor[d], 1);
        esrc[start[d] + p] = srcIdx[e];
    }
}

// ---- aggregate: O[n] = sum_{e in CSR[n]} H[esrc[e]] + bias  (+relu) ----
__global__ __launch_bounds__(256) void gather_nodes(const float* __restrict__ H,
                                                    const int* __restrict__ start,
                                                    const int* __restrict__ esrc,
                                                    const float* __restrict__ bias,
                                                    float* __restrict__ O,
                                                    int do_relu) {
    int node = blockIdx.x * 4 + (threadIdx.x >> 6);
    if (node >= NN) return;
    int lane = threadIdx.x & 63;
    int s0 = start[node], s1 = start[node + 1];
    float accx = 0.f, accy = 0.f;
    int i = s0;
    for (; i + 3 < s1; i += 4) {
        int sA = esrc[i], sB = esrc[i + 1], sC = esrc[i + 2], sD = esrc[i + 3];
        float2 a = *(const float2*)&H[sA * CH + lane * 2];
        float2 b = *(const float2*)&H[sB * CH + lane * 2];
        float2 c = *(const float2*)&H[sC * CH + lane * 2];
        float2 d = *(const float2*)&H[sD * CH + lane * 2];
        accx += (a.x + b.x) + (c.x + d.x);
        accy += (a.y + b.y) + (c.y + d.y);
    }
    for (; i < s1; ++i) {
        int sA = esrc[i];
        float2 a = *(const float2*)&H[sA * CH + lane * 2];
        accx += a.x;
        accy += a.y;
    }
    float2 bv = *(const float2*)&bias[lane * 2];
    accx += bv.x;
    accy += bv.y;
    if (do_relu) { accx = fmaxf(accx, 0.f); accy = fmaxf(accy, 0.f); }
    *(float2*)&O[node * CH + lane * 2] = make_float2(accx, accy);
}

extern "C" void kernel_launch(void* const* d_in, const int* in_sizes, int n_in,
                              void* d_out, int out_size, void* d_ws, size_t ws_size,
                              hipStream_t stream) {
    const float* v0 = (const float*)d_in[0];
    const int* edge = (const int*)d_in[1];   // [2, NE]: row0 = src, row1 = dst
    const float* W1 = (const float*)d_in[2];
    const float* b1 = (const float*)d_in[3];
    const float* W2 = (const float*)d_in[4];
    const float* b2 = (const float*)d_in[5];
    float* out = (float*)d_out;

    const int* srcIdx = edge;
    const int* dstIdx = edge + NE;

    // workspace layout
    float* bufA = (float*)d_ws;                   // [NN*CH] h1 / h2
    float* bufB = bufA + (size_t)NN * CH;         // [NN*CH] x (layer-1 output)
    int* cnt    = (int*)(bufB + (size_t)NN * CH); // [NN]
    int* cursor = cnt + NN;                       // [NN]
    int* start  = cursor + NN;                    // [NN+1]
    int* esrc   = start + (NN + 1);               // [NE]
    int* bsum   = esrc + NE;                      // [NBLK]
    int* bofs   = bsum + NBLK;                    // [NBLK]

    // --- build CSR (per call; deterministic structure) ---
    hipMemsetAsync(cnt, 0, 2 * (size_t)NN * sizeof(int), stream);  // cnt + cursor
    count_deg<<<(NE + 255) / 256, 256, 0, stream>>>(dstIdx, cnt);
    scan_bsum<<<NBLK, 256, 0, stream>>>(cnt, bsum);
    scan_bofs<<<1, 256, 0, stream>>>(bsum, bofs, start);
    scan_local<<<NBLK, 256, 0, stream>>>(cnt, bofs, start);
    fill_csr<<<(NE + 255) / 256, 256, 0, stream>>>(srcIdx, dstIdx, start, cursor, esrc);

    // --- layer 1: x = relu(A @ (v0 W1) + b1) ---
    gemm128<<<(NN + 31) / 32, 256, 0, stream>>>(v0, W1, bufA, NN);
    gather_nodes<<<(NN + 3) / 4, 256, 0, stream>>>(bufA, start, esrc, b1, bufB, 1);

    // --- layer 2: out = A @ (x W2) + b2 ---
    gemm128<<<(NN + 31) / 32, 256, 0, stream>>>(bufB, W2, bufA, NN);
    gather_nodes<<<(NN + 3) / 4, 256, 0, stream>>>(bufA, start, esrc, b2, out, 0);
}

// Round 4
// 179.443 us; speedup vs baseline: 12.7228x; 1.4977x over previous
//
#include <hip/hip_runtime.h>

#define NN 50000
#define NE 640000
#define CH 128
#define SCAN_B 256
#define NBLK ((NN + SCAN_B - 1) / SCAN_B)   // 196

typedef __attribute__((ext_vector_type(8))) short bf16x8;
typedef __attribute__((ext_vector_type(4))) float f32x4;

// f32 -> bf16 (RNE)
__device__ __forceinline__ unsigned short f2bf(float x) {
    unsigned int b = __float_as_uint(x);
    b += 0x7fffu + ((b >> 16) & 1u);
    return (unsigned short)(b >> 16);
}
// bf16 pair (packed in uint) -> f32, free bit-ops
__device__ __forceinline__ float bflo(unsigned int u) { return __uint_as_float(u << 16); }
__device__ __forceinline__ float bfhi(unsigned int u) { return __uint_as_float(u & 0xffff0000u); }

// ---- convert f32 array -> bf16 (ushort) array, 4 elems/thread ----
__global__ __launch_bounds__(256) void conv_bf16(const float* __restrict__ in,
                                                 unsigned short* __restrict__ out, int n4) {
    int i = blockIdx.x * 256 + threadIdx.x;
    if (i >= n4) return;
    float4 v = ((const float4*)in)[i];
    uint2 o;
    o.x = (unsigned)f2bf(v.x) | ((unsigned)f2bf(v.y) << 16);
    o.y = (unsigned)f2bf(v.z) | ((unsigned)f2bf(v.w) << 16);
    ((uint2*)out)[i] = o;
}

// ---- pack W1,W2 into MFMA A-fragment layout (bf16) ----
// frag f = ct*4+kb, lane l holds W[kb*32 + (l>>4)*8 + i][ct*16 + (l&15)], i=0..7
__global__ __launch_bounds__(256) void pack_w2(const float* __restrict__ W1,
                                               const float* __restrict__ W2,
                                               unsigned short* __restrict__ Wp) {
    int gid = blockIdx.x * 256 + threadIdx.x;   // [0, 4096)
    if (gid >= 4096) return;
    const float* W = (gid < 2048) ? W1 : W2;
    int g = gid & 2047;
    int f = g >> 6, l = g & 63;
    int ct = f >> 2, kb = f & 3;
    int col = ct * 16 + (l & 15);
    int k0 = kb * 32 + (l >> 4) * 8;
    unsigned short t[8];
#pragma unroll
    for (int i = 0; i < 8; ++i) t[i] = f2bf(W[(k0 + i) * CH + col]);
    uint4 v;
    v.x = (unsigned)t[0] | ((unsigned)t[1] << 16);
    v.y = (unsigned)t[2] | ((unsigned)t[3] << 16);
    v.z = (unsigned)t[4] | ((unsigned)t[5] << 16);
    v.w = (unsigned)t[6] | ((unsigned)t[7] << 16);
    ((uint4*)Wp)[gid] = v;
}

// ---- GEMM: Yb = Xb @ W (bf16 in/out, f32 accum, MFMA 16x16x32) ----
// 4 waves/block, wave w owns rows blockIdx*64 + w*16 .. +16, all 128 cols.
// Operand swap: A = W-col fragment (from LDS pack), B = X-row fragment ->
// D lane l holds Y[row=l&15][col=ct*16+(l>>4)*4+reg] : 4 consecutive cols -> 8B store.
__global__ __launch_bounds__(256) void gemm_mfma(const unsigned short* __restrict__ Xb,
                                                 const unsigned short* __restrict__ Wp,
                                                 unsigned short* __restrict__ Yb, int nrows) {
    __shared__ unsigned short WL[32 * 64 * 8];   // 32 KiB
    int tid = threadIdx.x;
#pragma unroll
    for (int i = 0; i < 8; ++i)
        ((uint4*)WL)[tid + i * 256] = ((const uint4*)Wp)[tid + i * 256];

    int w = tid >> 6, l = tid & 63;
    int row = blockIdx.x * 64 + w * 16 + (l & 15);
    int rc = min(row, nrows - 1);
    int kq = l >> 4;

    const uint4* xrow = (const uint4*)(Xb + (size_t)rc * CH);   // 16B units
    bf16x8 xf[4];
#pragma unroll
    for (int kb = 0; kb < 4; ++kb)
        xf[kb] = *(const bf16x8*)(xrow + kb * 4 + kq);

    __syncthreads();

    f32x4 acc[8];
#pragma unroll
    for (int ct = 0; ct < 8; ++ct) acc[ct] = (f32x4){0.f, 0.f, 0.f, 0.f};

#pragma unroll
    for (int ct = 0; ct < 8; ++ct)
#pragma unroll
        for (int kb = 0; kb < 4; ++kb) {
            bf16x8 wf = *(const bf16x8*)&WL[((ct * 4 + kb) * 64 + l) * 8];
            acc[ct] = __builtin_amdgcn_mfma_f32_16x16x32_bf16(wf, xf[kb], acc[ct], 0, 0, 0);
        }

    if (row < nrows) {
        unsigned short* yrow = Yb + (size_t)row * CH;
#pragma unroll
        for (int ct = 0; ct < 8; ++ct) {
            int col = ct * 16 + kq * 4;
            uint2 o;
            o.x = (unsigned)f2bf(acc[ct][0]) | ((unsigned)f2bf(acc[ct][1]) << 16);
            o.y = (unsigned)f2bf(acc[ct][2]) | ((unsigned)f2bf(acc[ct][3]) << 16);
            *(uint2*)(yrow + col) = o;
        }
    }
}

// ---- CSR build: count degrees ----
__global__ __launch_bounds__(256) void count_deg(const int* __restrict__ dstIdx,
                                                 int* __restrict__ cnt) {
    int e = blockIdx.x * 256 + threadIdx.x;
    if (e < NE) atomicAdd(&cnt[dstIdx[e]], 1);
}

// ---- scan level 1: per-block sums ----
__global__ __launch_bounds__(256) void scan_bsum(const int* __restrict__ cnt,
                                                 int* __restrict__ bsum) {
    __shared__ int sd[256];
    int i = blockIdx.x * 256 + threadIdx.x;
    sd[threadIdx.x] = (i < NN) ? cnt[i] : 0;
    __syncthreads();
    for (int off = 128; off > 0; off >>= 1) {
        if (threadIdx.x < off) sd[threadIdx.x] += sd[threadIdx.x + off];
        __syncthreads();
    }
    if (threadIdx.x == 0) bsum[blockIdx.x] = sd[0];
}

// ---- scan level 2: exclusive scan of block sums (1 block) ----
__global__ __launch_bounds__(256) void scan_bofs(const int* __restrict__ bsum,
                                                 int* __restrict__ bofs,
                                                 int* __restrict__ start) {
    __shared__ int buf[256];
    int t = threadIdx.x;
    int v = (t < NBLK) ? bsum[t] : 0;
    buf[t] = v;
    __syncthreads();
    for (int off = 1; off < 256; off <<= 1) {
        int u = (t >= off) ? buf[t - off] : 0;
        __syncthreads();
        buf[t] += u;
        __syncthreads();
    }
    if (t < NBLK) bofs[t] = buf[t] - v;
    if (t == 0) start[NN] = buf[NBLK - 1];
}

// ---- scan level 3: local exclusive scan + block offset ----
__global__ __launch_bounds__(256) void scan_local(const int* __restrict__ cnt,
                                                  const int* __restrict__ bofs,
                                                  int* __restrict__ start) {
    __shared__ int buf[256];
    int t = threadIdx.x;
    int i = blockIdx.x * 256 + t;
    int v = (i < NN) ? cnt[i] : 0;
    buf[t] = v;
    __syncthreads();
    for (int off = 1; off < 256; off <<= 1) {
        int u = (t >= off) ? buf[t - off] : 0;
        __syncthreads();
        buf[t] += u;
        __syncthreads();
    }
    if (i < NN) start[i] = bofs[blockIdx.x] + buf[t] - v;
}

// ---- CSR fill ----
__global__ __launch_bounds__(256) void fill_csr(const int* __restrict__ srcIdx,
                                                const int* __restrict__ dstIdx,
                                                const int* __restrict__ start,
                                                int* __restrict__ cursor,
                                                int* __restrict__ esrc) {
    int e = blockIdx.x * 256 + threadIdx.x;
    if (e < NE) {
        int d = dstIdx[e];
        int p = atomicAdd(&cursor[d], 1);
        esrc[start[d] + p] = srcIdx[e];
    }
}

// ---- aggregate (bf16 H): O[n] = sum H[esrc] + bias (+relu) ----
// one wave/node, 2 channels/lane (one uint), f32 accumulate.
// Obf!=null -> write bf16; else write f32 to Of32.
__global__ __launch_bounds__(256) void gather_bf16(const unsigned short* __restrict__ Hb,
                                                   const int* __restrict__ start,
                                                   const int* __restrict__ esrc,
                                                   const float* __restrict__ bias,
                                                   unsigned short* __restrict__ Obf,
                                                   float* __restrict__ Of32,
                                                   int do_relu) {
    int node = blockIdx.x * 4 + (threadIdx.x >> 6);
    if (node >= NN) return;
    int lane = threadIdx.x & 63;
    int s0 = start[node], s1 = start[node + 1];
    const unsigned int* H32 = (const unsigned int*)Hb;
    float ax = 0.f, ay = 0.f;
    int i = s0;
    for (; i + 3 < s1; i += 4) {
        int sA = esrc[i], sB = esrc[i + 1], sC = esrc[i + 2], sD = esrc[i + 3];
        unsigned int a = H32[sA * 64 + lane];
        unsigned int b = H32[sB * 64 + lane];
        unsigned int c = H32[sC * 64 + lane];
        unsigned int d = H32[sD * 64 + lane];
        ax += (bflo(a) + bflo(b)) + (bflo(c) + bflo(d));
        ay += (bfhi(a) + bfhi(b)) + (bfhi(c) + bfhi(d));
    }
    for (; i < s1; ++i) {
        unsigned int a = H32[esrc[i] * 64 + lane];
        ax += bflo(a);
        ay += bfhi(a);
    }
    float2 bv = *(const float2*)&bias[lane * 2];
    ax += bv.x;
    ay += bv.y;
    if (do_relu) { ax = fmaxf(ax, 0.f); ay = fmaxf(ay, 0.f); }
    if (Obf) {
        ((unsigned int*)Obf)[node * 64 + lane] =
            (unsigned)f2bf(ax) | ((unsigned)f2bf(ay) << 16);
    } else {
        *(float2*)&Of32[(size_t)node * CH + lane * 2] = make_float2(ax, ay);
    }
}

extern "C" void kernel_launch(void* const* d_in, const int* in_sizes, int n_in,
                              void* d_out, int out_size, void* d_ws, size_t ws_size,
                              hipStream_t stream) {
    const float* v0 = (const float*)d_in[0];
    const int* edge = (const int*)d_in[1];   // [2, NE]: row0 = src, row1 = dst
    const float* W1 = (const float*)d_in[2];
    const float* b1 = (const float*)d_in[3];
    const float* W2 = (const float*)d_in[4];
    const float* b2 = (const float*)d_in[5];
    float* out = (float*)d_out;

    const int* srcIdx = edge;
    const int* dstIdx = edge + NE;

    // workspace layout
    unsigned short* Xb0 = (unsigned short*)d_ws;      // [NN*CH] bf16 v0
    unsigned short* Xb1 = Xb0 + (size_t)NN * CH;      // [NN*CH] bf16 layer-1 act
    unsigned short* Hb  = Xb1 + (size_t)NN * CH;      // [NN*CH] bf16 h1/h2
    unsigned short* Wp  = Hb + (size_t)NN * CH;       // [2*16384] packed W1,W2
    int* cnt    = (int*)(Wp + 2 * 16384);             // [NN]
    int* cursor = cnt + NN;                           // [NN]
    int* start  = cursor + NN;                        // [NN+1]
    int* esrc   = start + (NN + 1);                   // [NE]
    int* bsum   = esrc + NE;                          // [NBLK]
    int* bofs   = bsum + NBLK;                        // [NBLK]

    // --- build CSR ---
    hipMemsetAsync(cnt, 0, 2 * (size_t)NN * sizeof(int), stream);  // cnt + cursor
    count_deg<<<(NE + 255) / 256, 256, 0, stream>>>(dstIdx, cnt);
    scan_bsum<<<NBLK, 256, 0, stream>>>(cnt, bsum);
    scan_bofs<<<1, 256, 0, stream>>>(bsum, bofs, start);
    scan_local<<<NBLK, 256, 0, stream>>>(cnt, bofs, start);
    fill_csr<<<(NE + 255) / 256, 256, 0, stream>>>(srcIdx, dstIdx, start, cursor, esrc);

    // --- convert inputs to bf16 / pack weights ---
    conv_bf16<<<(NN * CH / 4 + 255) / 256, 256, 0, stream>>>(v0, Xb0, NN * CH / 4);
    pack_w2<<<16, 256, 0, stream>>>(W1, W2, Wp);

    // --- layer 1: x = relu(A @ (v0 W1) + b1) ---
    gemm_mfma<<<(NN + 63) / 64, 256, 0, stream>>>(Xb0, Wp, Hb, NN);
    gather_bf16<<<(NN + 3) / 4, 256, 0, stream>>>(Hb, start, esrc, b1, Xb1, nullptr, 1);

    // --- layer 2: out = A @ (x W2) + b2 ---
    gemm_mfma<<<(NN + 63) / 64, 256, 0, stream>>>(Xb1, Wp + 16384, Hb, NN);
    gather_bf16<<<(NN + 3) / 4, 256, 0, stream>>>(Hb, start, esrc, b2, nullptr, out, 0);
}

// Round 5
// 179.116 us; speedup vs baseline: 12.7460x; 1.0018x over previous
//
#include <hip/hip_runtime.h>

#define NN 50000
#define NE 640000
#define CH 128
#define SCAN_B 256
#define NBLK ((NN + SCAN_B - 1) / SCAN_B)   // 196

typedef __attribute__((ext_vector_type(8))) short bf16x8;
typedef __attribute__((ext_vector_type(4))) float f32x4;

// f32 -> bf16 (RNE)
__device__ __forceinline__ unsigned short f2bf(float x) {
    unsigned int b = __float_as_uint(x);
    b += 0x7fffu + ((b >> 16) & 1u);
    return (unsigned short)(b >> 16);
}
// bf16 pair (packed in uint) -> f32, free bit-ops
__device__ __forceinline__ float bflo(unsigned int u) { return __uint_as_float(u << 16); }
__device__ __forceinline__ float bfhi(unsigned int u) { return __uint_as_float(u & 0xffff0000u); }

// ---- zero int buffer (uint4 stores) ----
__global__ __launch_bounds__(256) void zero_buf(uint4* __restrict__ p, int n16) {
    int i = blockIdx.x * 256 + threadIdx.x;
    if (i < n16) p[i] = make_uint4(0u, 0u, 0u, 0u);
}

// ---- convert f32 array -> bf16 (ushort) array, 4 elems/thread ----
__global__ __launch_bounds__(256) void conv_bf16(const float* __restrict__ in,
                                                 unsigned short* __restrict__ out, int n4) {
    int i = blockIdx.x * 256 + threadIdx.x;
    if (i >= n4) return;
    float4 v = ((const float4*)in)[i];
    uint2 o;
    o.x = (unsigned)f2bf(v.x) | ((unsigned)f2bf(v.y) << 16);
    o.y = (unsigned)f2bf(v.z) | ((unsigned)f2bf(v.w) << 16);
    ((uint2*)out)[i] = o;
}

// ---- pack W1,W2 into MFMA A-fragment layout (bf16) ----
// frag f = ct*4+kb, lane l holds W[kb*32 + (l>>4)*8 + i][ct*16 + (l&15)], i=0..7
__global__ __launch_bounds__(256) void pack_w2(const float* __restrict__ W1,
                                               const float* __restrict__ W2,
                                               unsigned short* __restrict__ Wp) {
    int gid = blockIdx.x * 256 + threadIdx.x;   // [0, 4096)
    if (gid >= 4096) return;
    const float* W = (gid < 2048) ? W1 : W2;
    int g = gid & 2047;
    int f = g >> 6, l = g & 63;
    int ct = f >> 2, kb = f & 3;
    int col = ct * 16 + (l & 15);
    int k0 = kb * 32 + (l >> 4) * 8;
    unsigned short t[8];
#pragma unroll
    for (int i = 0; i < 8; ++i) t[i] = f2bf(W[(k0 + i) * CH + col]);
    uint4 v;
    v.x = (unsigned)t[0] | ((unsigned)t[1] << 16);
    v.y = (unsigned)t[2] | ((unsigned)t[3] << 16);
    v.z = (unsigned)t[4] | ((unsigned)t[5] << 16);
    v.w = (unsigned)t[6] | ((unsigned)t[7] << 16);
    ((uint4*)Wp)[gid] = v;
}

// ---- GEMM: Yb = Xb @ W (bf16 in/out, f32 accum, MFMA 16x16x32) ----
__global__ __launch_bounds__(256) void gemm_mfma(const unsigned short* __restrict__ Xb,
                                                 const unsigned short* __restrict__ Wp,
                                                 unsigned short* __restrict__ Yb, int nrows) {
    __shared__ unsigned short WL[32 * 64 * 8];   // 32 KiB
    int tid = threadIdx.x;
#pragma unroll
    for (int i = 0; i < 8; ++i)
        ((uint4*)WL)[tid + i * 256] = ((const uint4*)Wp)[tid + i * 256];

    int w = tid >> 6, l = tid & 63;
    int row = blockIdx.x * 64 + w * 16 + (l & 15);
    int rc = min(row, nrows - 1);
    int kq = l >> 4;

    const uint4* xrow = (const uint4*)(Xb + (size_t)rc * CH);   // 16B units
    bf16x8 xf[4];
#pragma unroll
    for (int kb = 0; kb < 4; ++kb)
        xf[kb] = *(const bf16x8*)(xrow + kb * 4 + kq);

    __syncthreads();

    f32x4 acc[8];
#pragma unroll
    for (int ct = 0; ct < 8; ++ct) acc[ct] = (f32x4){0.f, 0.f, 0.f, 0.f};

#pragma unroll
    for (int ct = 0; ct < 8; ++ct)
#pragma unroll
        for (int kb = 0; kb < 4; ++kb) {
            bf16x8 wf = *(const bf16x8*)&WL[((ct * 4 + kb) * 64 + l) * 8];
            acc[ct] = __builtin_amdgcn_mfma_f32_16x16x32_bf16(wf, xf[kb], acc[ct], 0, 0, 0);
        }

    if (row < nrows) {
        unsigned short* yrow = Yb + (size_t)row * CH;
#pragma unroll
        for (int ct = 0; ct < 8; ++ct) {
            int col = ct * 16 + kq * 4;
            uint2 o;
            o.x = (unsigned)f2bf(acc[ct][0]) | ((unsigned)f2bf(acc[ct][1]) << 16);
            o.y = (unsigned)f2bf(acc[ct][2]) | ((unsigned)f2bf(acc[ct][3]) << 16);
            *(uint2*)(yrow + col) = o;
        }
    }
}

// ---- CSR build: count degrees ----
__global__ __launch_bounds__(256) void count_deg(const int* __restrict__ dstIdx,
                                                 int* __restrict__ cnt) {
    int e = blockIdx.x * 256 + threadIdx.x;
    if (e < NE) atomicAdd(&cnt[dstIdx[e]], 1);
}

// ---- scan level 1: per-block sums ----
__global__ __launch_bounds__(256) void scan_bsum(const int* __restrict__ cnt,
                                                 int* __restrict__ bsum) {
    __shared__ int sd[256];
    int i = blockIdx.x * 256 + threadIdx.x;
    sd[threadIdx.x] = (i < NN) ? cnt[i] : 0;
    __syncthreads();
    for (int off = 128; off > 0; off >>= 1) {
        if (threadIdx.x < off) sd[threadIdx.x] += sd[threadIdx.x + off];
        __syncthreads();
    }
    if (threadIdx.x == 0) bsum[blockIdx.x] = sd[0];
}

// ---- scan level 2: exclusive scan of block sums (1 block) ----
__global__ __launch_bounds__(256) void scan_bofs(const int* __restrict__ bsum,
                                                 int* __restrict__ bofs,
                                                 int* __restrict__ start) {
    __shared__ int buf[256];
    int t = threadIdx.x;
    int v = (t < NBLK) ? bsum[t] : 0;
    buf[t] = v;
    __syncthreads();
    for (int off = 1; off < 256; off <<= 1) {
        int u = (t >= off) ? buf[t - off] : 0;
        __syncthreads();
        buf[t] += u;
        __syncthreads();
    }
    if (t < NBLK) bofs[t] = buf[t] - v;
    if (t == 0) start[NN] = buf[NBLK - 1];
}

// ---- scan level 3: local exclusive scan + block offset ----
__global__ __launch_bounds__(256) void scan_local(const int* __restrict__ cnt,
                                                  const int* __restrict__ bofs,
                                                  int* __restrict__ start) {
    __shared__ int buf[256];
    int t = threadIdx.x;
    int i = blockIdx.x * 256 + t;
    int v = (i < NN) ? cnt[i] : 0;
    buf[t] = v;
    __syncthreads();
    for (int off = 1; off < 256; off <<= 1) {
        int u = (t >= off) ? buf[t - off] : 0;
        __syncthreads();
        buf[t] += u;
        __syncthreads();
    }
    if (i < NN) start[i] = bofs[blockIdx.x] + buf[t] - v;
}

// ---- CSR fill ----
__global__ __launch_bounds__(256) void fill_csr(const int* __restrict__ srcIdx,
                                                const int* __restrict__ dstIdx,
                                                const int* __restrict__ start,
                                                int* __restrict__ cursor,
                                                int* __restrict__ esrc) {
    int e = blockIdx.x * 256 + threadIdx.x;
    if (e < NE) {
        int d = dstIdx[e];
        int p = atomicAdd(&cursor[d], 1);
        esrc[start[d] + p] = srcIdx[e];
    }
}

// ---- aggregate (bf16 H): O[n] = sum H[esrc] + bias (+relu) ----
__global__ __launch_bounds__(256) void gather_bf16(const unsigned short* __restrict__ Hb,
                                                   const int* __restrict__ start,
                                                   const int* __restrict__ esrc,
                                                   const float* __restrict__ bias,
                                                   unsigned short* __restrict__ Obf,
                                                   float* __restrict__ Of32,
                                                   int do_relu) {
    int node = blockIdx.x * 4 + (threadIdx.x >> 6);
    if (node >= NN) return;
    int lane = threadIdx.x & 63;
    int s0 = start[node], s1 = start[node + 1];
    const unsigned int* H32 = (const unsigned int*)Hb;
    float ax = 0.f, ay = 0.f;
    int i = s0;
    for (; i + 3 < s1; i += 4) {
        int sA = esrc[i], sB = esrc[i + 1], sC = esrc[i + 2], sD = esrc[i + 3];
        unsigned int a = H32[sA * 64 + lane];
        unsigned int b = H32[sB * 64 + lane];
        unsigned int c = H32[sC * 64 + lane];
        unsigned int d = H32[sD * 64 + lane];
        ax += (bflo(a) + bflo(b)) + (bflo(c) + bflo(d));
        ay += (bfhi(a) + bfhi(b)) + (bfhi(c) + bfhi(d));
    }
    for (; i < s1; ++i) {
        unsigned int a = H32[esrc[i] * 64 + lane];
        ax += bflo(a);
        ay += bfhi(a);
    }
    float2 bv = *(const float2*)&bias[lane * 2];
    ax += bv.x;
    ay += bv.y;
    if (do_relu) { ax = fmaxf(ax, 0.f); ay = fmaxf(ay, 0.f); }
    if (Obf) {
        ((unsigned int*)Obf)[node * 64 + lane] =
            (unsigned)f2bf(ax) | ((unsigned)f2bf(ay) << 16);
    } else {
        *(float2*)&Of32[(size_t)node * CH + lane * 2] = make_float2(ax, ay);
    }
}

extern "C" void kernel_launch(void* const* d_in, const int* in_sizes, int n_in,
                              void* d_out, int out_size, void* d_ws, size_t ws_size,
                              hipStream_t stream) {
    const float* v0 = (const float*)d_in[0];
    const int* edge = (const int*)d_in[1];   // [2, NE]: row0 = src, row1 = dst
    const float* W1 = (const float*)d_in[2];
    const float* b1 = (const float*)d_in[3];
    const float* W2 = (const float*)d_in[4];
    const float* b2 = (const float*)d_in[5];
    float* out = (float*)d_out;

    const int* srcIdx = edge;
    const int* dstIdx = edge + NE;

    // workspace layout
    unsigned short* Xb0 = (unsigned short*)d_ws;      // [NN*CH] bf16 v0
    unsigned short* Xb1 = Xb0 + (size_t)NN * CH;      // [NN*CH] bf16 layer-1 act
    unsigned short* Hb  = Xb1 + (size_t)NN * CH;      // [NN*CH] bf16 h1/h2
    unsigned short* Wp  = Hb + (size_t)NN * CH;       // [2*16384] packed W1,W2
    int* cnt    = (int*)(Wp + 2 * 16384);             // [NN]
    int* cursor = cnt + NN;                           // [NN]  (contiguous with cnt)
    int* start  = cursor + NN;                        // [NN+1]
    int* esrc   = start + (NN + 1);                   // [NE]
    int* bsum   = esrc + NE;                          // [NBLK]
    int* bofs   = bsum + NBLK;                        // [NBLK]

    // --- build CSR ---
    const int n16 = (2 * NN) / 4;   // cnt+cursor as uint4 count (2*NN divisible by 4)
    zero_buf<<<(n16 + 255) / 256, 256, 0, stream>>>((uint4*)cnt, n16);
    count_deg<<<(NE + 255) / 256, 256, 0, stream>>>(dstIdx, cnt);
    scan_bsum<<<NBLK, 256, 0, stream>>>(cnt, bsum);
    scan_bofs<<<1, 256, 0, stream>>>(bsum, bofs, start);
    scan_local<<<NBLK, 256, 0, stream>>>(cnt, bofs, start);
    fill_csr<<<(NE + 255) / 256, 256, 0, stream>>>(srcIdx, dstIdx, start, cursor, esrc);

    // --- convert inputs to bf16 / pack weights ---
    conv_bf16<<<(NN * CH / 4 + 255) / 256, 256, 0, stream>>>(v0, Xb0, NN * CH / 4);
    pack_w2<<<16, 256, 0, stream>>>(W1, W2, Wp);

    // --- layer 1: x = relu(A @ (v0 W1) + b1) ---
    gemm_mfma<<<(NN + 63) / 64, 256, 0, stream>>>(Xb0, Wp, Hb, NN);
    gather_bf16<<<(NN + 3) / 4, 256, 0, stream>>>(Hb, start, esrc, b1, Xb1, nullptr, 1);

    // --- layer 2: out = A @ (x W2) + b2 ---
    gemm_mfma<<<(NN + 63) / 64, 256, 0, stream>>>(Xb1, Wp + 16384, Hb, NN);
    gather_bf16<<<(NN + 3) / 4, 256, 0, stream>>>(Hb, start, esrc, b2, nullptr, out, 0);
}

// Round 6
// 167.079 us; speedup vs baseline: 13.6643x; 1.0720x over previous
//
#include <hip/hip_runtime.h>

#define NN 50000
#define NE 640000
#define CH 128
#define SCAN_B 256
#define NBLK ((NN + SCAN_B - 1) / SCAN_B)   // 196

typedef __attribute__((ext_vector_type(8))) short bf16x8;
typedef __attribute__((ext_vector_type(4))) float f32x4;

// f32 -> bf16 (RNE)
__device__ __forceinline__ unsigned short f2bf(float x) {
    unsigned int b = __float_as_uint(x);
    b += 0x7fffu + ((b >> 16) & 1u);
    return (unsigned short)(b >> 16);
}
// bf16 pair (packed in uint) -> f32, free bit-ops
__device__ __forceinline__ float bflo(unsigned int u) { return __uint_as_float(u << 16); }
__device__ __forceinline__ float bfhi(unsigned int u) { return __uint_as_float(u & 0xffff0000u); }

// ---- prep: zero cnt (blocks 0..48) + pack W1,W2 to MFMA frag layout (blocks 49..64) ----
__global__ __launch_bounds__(256) void prep(uint4* __restrict__ cntz,
                                            const float* __restrict__ W1,
                                            const float* __restrict__ W2,
                                            unsigned short* __restrict__ Wp) {
    int b = blockIdx.x;
    if (b < 49) {
        int i = b * 256 + threadIdx.x;          // cnt = 50000 ints = 12500 uint4
        if (i < 12500) cntz[i] = make_uint4(0u, 0u, 0u, 0u);
        return;
    }
    int gid = (b - 49) * 256 + threadIdx.x;     // [0, 4096)
    if (gid >= 4096) return;
    const float* W = (gid < 2048) ? W1 : W2;
    int g = gid & 2047;
    int f = g >> 6, l = g & 63;
    int ct = f >> 2, kb = f & 3;
    int col = ct * 16 + (l & 15);
    int k0 = kb * 32 + (l >> 4) * 8;
    unsigned short t[8];
#pragma unroll
    for (int i = 0; i < 8; ++i) t[i] = f2bf(W[(k0 + i) * CH + col]);
    uint4 v;
    v.x = (unsigned)t[0] | ((unsigned)t[1] << 16);
    v.y = (unsigned)t[2] | ((unsigned)t[3] << 16);
    v.z = (unsigned)t[4] | ((unsigned)t[5] << 16);
    v.w = (unsigned)t[6] | ((unsigned)t[7] << 16);
    ((uint4*)Wp)[gid] = v;
}

// ---- GEMM: Yb = X @ W (bf16 MFMA 16x16x32, f32 accum). F32IN: X is f32, else bf16 ----
template <int F32IN>
__global__ __launch_bounds__(256) void gemm_mfma(const void* __restrict__ Xin,
                                                 const unsigned short* __restrict__ Wp,
                                                 unsigned short* __restrict__ Yb, int nrows) {
    __shared__ unsigned short WL[32 * 64 * 8];   // 32 KiB
    int tid = threadIdx.x;
#pragma unroll
    for (int i = 0; i < 8; ++i)
        ((uint4*)WL)[tid + i * 256] = ((const uint4*)Wp)[tid + i * 256];

    int w = tid >> 6, l = tid & 63;
    int row = blockIdx.x * 64 + w * 16 + (l & 15);
    int rc = min(row, nrows - 1);
    int kq = l >> 4;

    bf16x8 xf[4];
    if (F32IN) {
        const float* Xf = (const float*)Xin;
#pragma unroll
        for (int kb = 0; kb < 4; ++kb) {
            const float* p = Xf + (size_t)rc * CH + kb * 32 + kq * 8;
            float4 a = *(const float4*)p;
            float4 bq = *(const float4*)(p + 4);
            union { bf16x8 v; unsigned int u[4]; } r;
            r.u[0] = (unsigned)f2bf(a.x) | ((unsigned)f2bf(a.y) << 16);
            r.u[1] = (unsigned)f2bf(a.z) | ((unsigned)f2bf(a.w) << 16);
            r.u[2] = (unsigned)f2bf(bq.x) | ((unsigned)f2bf(bq.y) << 16);
            r.u[3] = (unsigned)f2bf(bq.z) | ((unsigned)f2bf(bq.w) << 16);
            xf[kb] = r.v;
        }
    } else {
        const uint4* xrow = (const uint4*)((const unsigned short*)Xin + (size_t)rc * CH);
#pragma unroll
        for (int kb = 0; kb < 4; ++kb)
            xf[kb] = *(const bf16x8*)(xrow + kb * 4 + kq);
    }

    __syncthreads();

    f32x4 acc[8];
#pragma unroll
    for (int ct = 0; ct < 8; ++ct) acc[ct] = (f32x4){0.f, 0.f, 0.f, 0.f};

#pragma unroll
    for (int ct = 0; ct < 8; ++ct)
#pragma unroll
        for (int kb = 0; kb < 4; ++kb) {
            bf16x8 wf = *(const bf16x8*)&WL[((ct * 4 + kb) * 64 + l) * 8];
            acc[ct] = __builtin_amdgcn_mfma_f32_16x16x32_bf16(wf, xf[kb], acc[ct], 0, 0, 0);
        }

    if (row < nrows) {
        unsigned short* yrow = Yb + (size_t)row * CH;
#pragma unroll
        for (int ct = 0; ct < 8; ++ct) {
            int col = ct * 16 + kq * 4;
            uint2 o;
            o.x = (unsigned)f2bf(acc[ct][0]) | ((unsigned)f2bf(acc[ct][1]) << 16);
            o.y = (unsigned)f2bf(acc[ct][2]) | ((unsigned)f2bf(acc[ct][3]) << 16);
            *(uint2*)(yrow + col) = o;
        }
    }
}

// ---- CSR build: count degrees ----
__global__ __launch_bounds__(256) void count_deg(const int* __restrict__ dstIdx,
                                                 int* __restrict__ cnt) {
    int e = blockIdx.x * 256 + threadIdx.x;
    if (e < NE) atomicAdd(&cnt[dstIdx[e]], 1);
}

// ---- scan level 1: per-block sums ----
__global__ __launch_bounds__(256) void scan_bsum(const int* __restrict__ cnt,
                                                 int* __restrict__ bsum) {
    __shared__ int sd[256];
    int i = blockIdx.x * 256 + threadIdx.x;
    sd[threadIdx.x] = (i < NN) ? cnt[i] : 0;
    __syncthreads();
    for (int off = 128; off > 0; off >>= 1) {
        if (threadIdx.x < off) sd[threadIdx.x] += sd[threadIdx.x + off];
        __syncthreads();
    }
    if (threadIdx.x == 0) bsum[blockIdx.x] = sd[0];
}

// ---- scan level 2: exclusive scan of block sums (1 block) ----
__global__ __launch_bounds__(256) void scan_bofs(const int* __restrict__ bsum,
                                                 int* __restrict__ bofs,
                                                 int* __restrict__ start) {
    __shared__ int buf[256];
    int t = threadIdx.x;
    int v = (t < NBLK) ? bsum[t] : 0;
    buf[t] = v;
    __syncthreads();
    for (int off = 1; off < 256; off <<= 1) {
        int u = (t >= off) ? buf[t - off] : 0;
        __syncthreads();
        buf[t] += u;
        __syncthreads();
    }
    if (t < NBLK) bofs[t] = buf[t] - v;
    if (t == 0) start[NN] = buf[NBLK - 1];
}

// ---- scan level 3: local exclusive scan + block offset; seeds cursor = start ----
__global__ __launch_bounds__(256) void scan_local(const int* __restrict__ cnt,
                                                  const int* __restrict__ bofs,
                                                  int* __restrict__ start,
                                                  int* __restrict__ cursor) {
    __shared__ int buf[256];
    int t = threadIdx.x;
    int i = blockIdx.x * 256 + t;
    int v = (i < NN) ? cnt[i] : 0;
    buf[t] = v;
    __syncthreads();
    for (int off = 1; off < 256; off <<= 1) {
        int u = (t >= off) ? buf[t - off] : 0;
        __syncthreads();
        buf[t] += u;
        __syncthreads();
    }
    if (i < NN) {
        int s = bofs[blockIdx.x] + buf[t] - v;
        start[i] = s;
        cursor[i] = s;
    }
}

// ---- CSR fill (absolute cursor) ----
__global__ __launch_bounds__(256) void fill_csr(const int* __restrict__ srcIdx,
                                                const int* __restrict__ dstIdx,
                                                int* __restrict__ cursor,
                                                int* __restrict__ esrc) {
    int e = blockIdx.x * 256 + threadIdx.x;
    if (e < NE) {
        int p = atomicAdd(&cursor[dstIdx[e]], 1);
        esrc[p] = srcIdx[e];
    }
}

// ---- aggregate: O[n] = sum H[esrc] + bias (+relu). 4 edges/iter, 16 lanes/edge ----
// lane = q*16 + t: group q handles edge i+q, sublane t loads uint4 = channels [8t,8t+8)
__global__ __launch_bounds__(256) void gather4(const uint4* __restrict__ H128,
                                               const int* __restrict__ start,
                                               const int* __restrict__ esrc,
                                               const float* __restrict__ bias,
                                               unsigned short* __restrict__ Obf,
                                               float* __restrict__ Of32,
                                               int do_relu) {
    int node = blockIdx.x * 4 + (threadIdx.x >> 6);
    if (node >= NN) return;
    int l = threadIdx.x & 63;
    int q = l >> 4, t = l & 15;
    int s0 = start[node], s1 = start[node + 1];

    float acc[8];
#pragma unroll
    for (int k = 0; k < 8; ++k) acc[k] = 0.f;

    for (int i = s0; i < s1; i += 4) {
        int j = i + q;
        float m = (j < s1) ? 1.f : 0.f;
        int jj = min(j, s1 - 1);
        int idx = esrc[jj];
        uint4 v = H128[(size_t)idx * 16 + t];
        acc[0] = fmaf(m, bflo(v.x), acc[0]);
        acc[1] = fmaf(m, bfhi(v.x), acc[1]);
        acc[2] = fmaf(m, bflo(v.y), acc[2]);
        acc[3] = fmaf(m, bfhi(v.y), acc[3]);
        acc[4] = fmaf(m, bflo(v.z), acc[4]);
        acc[5] = fmaf(m, bfhi(v.z), acc[5]);
        acc[6] = fmaf(m, bflo(v.w), acc[6]);
        acc[7] = fmaf(m, bfhi(v.w), acc[7]);
    }

    // combine the 4 edge-groups (lanes t, 16+t, 32+t, 48+t hold same channels)
#pragma unroll
    for (int k = 0; k < 8; ++k) {
        acc[k] += __shfl_xor(acc[k], 16);
        acc[k] += __shfl_xor(acc[k], 32);
    }

    float4 b0 = *(const float4*)&bias[t * 8];
    float4 b1 = *(const float4*)&bias[t * 8 + 4];
    acc[0] += b0.x; acc[1] += b0.y; acc[2] += b0.z; acc[3] += b0.w;
    acc[4] += b1.x; acc[5] += b1.y; acc[6] += b1.z; acc[7] += b1.w;
    if (do_relu) {
#pragma unroll
        for (int k = 0; k < 8; ++k) acc[k] = fmaxf(acc[k], 0.f);
    }

    if (q == 0) {
        if (Obf) {
            uint4 o;
            o.x = (unsigned)f2bf(acc[0]) | ((unsigned)f2bf(acc[1]) << 16);
            o.y = (unsigned)f2bf(acc[2]) | ((unsigned)f2bf(acc[3]) << 16);
            o.z = (unsigned)f2bf(acc[4]) | ((unsigned)f2bf(acc[5]) << 16);
            o.w = (unsigned)f2bf(acc[6]) | ((unsigned)f2bf(acc[7]) << 16);
            ((uint4*)Obf)[(size_t)node * 16 + t] = o;
        } else {
            float* p = Of32 + (size_t)node * CH + t * 8;
            *(float4*)p = make_float4(acc[0], acc[1], acc[2], acc[3]);
            *(float4*)(p + 4) = make_float4(acc[4], acc[5], acc[6], acc[7]);
        }
    }
}

extern "C" void kernel_launch(void* const* d_in, const int* in_sizes, int n_in,
                              void* d_out, int out_size, void* d_ws, size_t ws_size,
                              hipStream_t stream) {
    const float* v0 = (const float*)d_in[0];
    const int* edge = (const int*)d_in[1];   // [2, NE]: row0 = src, row1 = dst
    const float* W1 = (const float*)d_in[2];
    const float* b1 = (const float*)d_in[3];
    const float* W2 = (const float*)d_in[4];
    const float* b2 = (const float*)d_in[5];
    float* out = (float*)d_out;

    const int* srcIdx = edge;
    const int* dstIdx = edge + NE;

    // workspace layout
    unsigned short* Xb1 = (unsigned short*)d_ws;      // [NN*CH] bf16 layer-1 act
    unsigned short* Hb  = Xb1 + (size_t)NN * CH;      // [NN*CH] bf16 h1/h2
    unsigned short* Wp  = Hb + (size_t)NN * CH;       // [2*16384] packed W1,W2
    int* cnt    = (int*)(Wp + 2 * 16384);             // [NN]
    int* cursor = cnt + NN;                           // [NN]
    int* start  = cursor + NN;                        // [NN+1]
    int* esrc   = start + (NN + 1);                   // [NE]
    int* bsum   = esrc + NE;                          // [NBLK]
    int* bofs   = bsum + NBLK;                        // [NBLK]

    // --- prep: zero cnt + pack weights (one kernel) ---
    prep<<<65, 256, 0, stream>>>((uint4*)cnt, W1, W2, Wp);

    // --- build CSR ---
    count_deg<<<(NE + 255) / 256, 256, 0, stream>>>(dstIdx, cnt);
    scan_bsum<<<NBLK, 256, 0, stream>>>(cnt, bsum);
    scan_bofs<<<1, 256, 0, stream>>>(bsum, bofs, start);
    scan_local<<<NBLK, 256, 0, stream>>>(cnt, bofs, start, cursor);
    fill_csr<<<(NE + 255) / 256, 256, 0, stream>>>(srcIdx, dstIdx, cursor, esrc);

    // --- layer 1: x = relu(A @ (v0 W1) + b1) ---
    gemm_mfma<1><<<(NN + 63) / 64, 256, 0, stream>>>(v0, Wp, Hb, NN);
    gather4<<<(NN + 3) / 4, 256, 0, stream>>>((const uint4*)Hb, start, esrc, b1, Xb1, nullptr, 1);

    // --- layer 2: out = A @ (x W2) + b2 ---
    gemm_mfma<0><<<(NN + 63) / 64, 256, 0, stream>>>(Xb1, Wp + 16384, Hb, NN);
    gather4<<<(NN + 3) / 4, 256, 0, stream>>>((const uint4*)Hb, start, esrc, b2, nullptr, out, 0);
}